// Round 11
// baseline (324.445 us; speedup 1.0000x reference)
//
#include <hip/hip_runtime.h>
#include <hip/hip_fp16.h>

#define NN 50000
#define NE 800000
// IN_C=16, EDGE_IN=16, HID=32, HEADS=4, HC=128
#define NB 196            // coarse buckets = ceil(NN/256)
#define EPB 3125          // edges per bucket-build block (NE/256)
#define NODE_BLOCKS 12500 // NN/4

// scale folded into all alpha components: log2(e)/sqrt(32)
#define SL 0.25506413f

// ---------------- Kernel 0: weight precompute --------------------------
__global__ __launch_bounds__(256) void precompute_kernel(
    const float* __restrict__ Wq, const float* __restrict__ Wk,
    const float* __restrict__ bq, const float* __restrict__ bk,
    float* __restrict__ Mbuf) {
  int t = threadIdx.x;
  for (int idx = t; idx < 1024; idx += 256) {
    int h = idx >> 8, i = (idx >> 4) & 15, j = idx & 15;
    float acc = 0.f;
#pragma unroll
    for (int c = 0; c < 32; c++)
      acc += Wq[i * 128 + h * 32 + c] * Wk[j * 128 + h * 32 + c];
    Mbuf[idx] = acc * SL;
  }
  if (t < 4) {
    float acc = 0.f;
#pragma unroll
    for (int c = 0; c < 32; c++) acc += bq[t * 32 + c] * bk[t * 32 + c];
    Mbuf[1024 + t] = acc * SL;
  }
}

// ---------------- Kernel 1: node precompute + coarse hist (fused) ------
__global__ __launch_bounds__(256) void node_linear_kernel(
    const float* __restrict__ x,
    const float* __restrict__ Wq, const float* __restrict__ bq,
    const float* __restrict__ Wk, const float* __restrict__ bk,
    const float* __restrict__ We, const float* __restrict__ Mbuf,
    const int* __restrict__ ei, int* __restrict__ hist_all,
    float* __restrict__ y, float* __restrict__ qe,
    float* __restrict__ u4, float* __restrict__ w4) {
  __shared__ int hist[NB];
  if (blockIdx.x >= NODE_BLOCKS) {
    int b = blockIdx.x - NODE_BLOCKS;  // [0,256)
    int t = threadIdx.x;
    if (t < NB) hist[t] = 0;
    __syncthreads();
    int base = b * EPB;
    for (int i = t; i < EPB; i += 256)
      atomicAdd(&hist[ei[NE + base + i] >> 8], 1);
    __syncthreads();
    if (t < NB) hist_all[t * 256 + b] = hist[t];
    return;
  }
  int wave = threadIdx.x >> 6;
  int lane = threadIdx.x & 63;
  int n = blockIdx.x * 4 + wave;
  int h = lane >> 4, t = lane & 15, base = h * 32 + t;
  int gb = lane & 48;

  float xr[16];
#pragma unroll
  for (int i = 0; i < 16; i++) xr[i] = x[n * 16 + i];

  float bqb = bq[base], bq16 = bq[base + 16];
  float bkb = bk[base], bk16 = bk[base + 16];
  float qb = bqb, q16 = bq16;
  float kb = bkb, k16 = bk16;
#pragma unroll
  for (int i = 0; i < 16; i++) {
    qb  += xr[i] * Wq[i * 128 + base];
    q16 += xr[i] * Wq[i * 128 + base + 16];
    kb  += xr[i] * Wk[i * 128 + base];
    k16 += xr[i] * Wk[i * 128 + base + 16];
  }

  // y_ht = sum_i x_i * M[h][i][t]  (M pre-scaled by SL)
  float yt = 0.f;
#pragma unroll
  for (int i = 0; i < 16; i++) yt += xr[i] * Mbuf[h * 256 + i * 16 + t];
  y[n * 64 + lane] = yt;

  // qe[h][t] = SL * sum_c q[h*32+c] * We[t*128 + h*32 + c]
  float acc = 0.f;
#pragma unroll
  for (int i = 0; i < 16; i++) {
    float qv  = __shfl(qb,  gb | i);
    float qv2 = __shfl(q16, gb | i);
    acc += qv * We[t * 128 + h * 32 + i] + qv2 * We[t * 128 + h * 32 + 16 + i];
  }
  qe[n * 64 + lane] = acc * SL;

  // u_h = SL*(q_h . bk_h) - SL*(bq_h . bk_h);  w_h = SL*(bq_h . k_h)
  float pu = qb * bkb + q16 * bk16;
  float pw = bqb * kb + bq16 * k16;
  pu += __shfl_xor(pu, 1); pw += __shfl_xor(pw, 1);
  pu += __shfl_xor(pu, 2); pw += __shfl_xor(pw, 2);
  pu += __shfl_xor(pu, 4); pw += __shfl_xor(pw, 4);
  pu += __shfl_xor(pu, 8); pw += __shfl_xor(pw, 8);
  if (t == 0) {
    u4[n * 4 + h] = pu * SL - Mbuf[1024 + h];
    w4[n * 4 + h] = pw * SL;
  }
}

// ---------------- CSR build ---------------------------------------------
__global__ __launch_bounds__(256) void scan_buckets_kernel(
    int* __restrict__ hist_all, int* __restrict__ btot) {
  int wv = blockIdx.x * 4 + (threadIdx.x >> 6);
  int l = threadIdx.x & 63;
  if (wv >= NB) return;
  int base = wv * 256;
  int run = 0;
#pragma unroll
  for (int c = 0; c < 4; c++) {
    int v = hist_all[base + c * 64 + l];
    int orig = v;
#pragma unroll
    for (int d = 1; d < 64; d <<= 1) {
      int u = __shfl_up(v, d);
      if (l >= d) v += u;
    }
    hist_all[base + c * 64 + l] = run + v - orig;
    run += __shfl(v, 63);
  }
  if (l == 0) btot[wv] = run;
}

__global__ __launch_bounds__(256) void tiny_scan_kernel(
    const int* __restrict__ btot, int* __restrict__ coarse_offs) {
  __shared__ int sc[256];
  int t = threadIdx.x;
  int v = (t < NB) ? btot[t] : 0;
  sc[t] = v;
  __syncthreads();
  for (int d = 1; d < 256; d <<= 1) {
    int u = (t >= d) ? sc[t - d] : 0;
    __syncthreads();
    sc[t] += u;
    __syncthreads();
  }
  if (t < NB) coarse_offs[t] = sc[t] - v;
  if (t == NB - 1) coarse_offs[NB] = sc[t];
}

// scatter edges into coarse-bucket order, carrying {src,eid} + ea f16
__global__ __launch_bounds__(256) void bucket_scatter_kernel(
    const int* __restrict__ ei, const float* __restrict__ edge_attr,
    const int* __restrict__ cursor_all, const int* __restrict__ coarse_offs,
    int2* __restrict__ s_tmp, uint4* __restrict__ ea_tmp) {
  __shared__ int cur[NB];
  int t = threadIdx.x, b = blockIdx.x;
  if (t < NB) cur[t] = cursor_all[t * 256 + b] + coarse_offs[t];
  __syncthreads();
  int base = b * EPB;
  for (int i = t; i < EPB; i += 256) {
    int e = base + i;
    int src = ei[e], dst = ei[NE + e];
    const float4* eap = (const float4*)(edge_attr + (size_t)e * 16);
    float4 a = eap[0], bb = eap[1], c = eap[2], d = eap[3];
    uint4 u0, u1;
    __half2 hh;
    hh = __floats2half2_rn(a.x, a.y);   u0.x = *(unsigned*)&hh;
    hh = __floats2half2_rn(a.z, a.w);   u0.y = *(unsigned*)&hh;
    hh = __floats2half2_rn(bb.x, bb.y); u0.z = *(unsigned*)&hh;
    hh = __floats2half2_rn(bb.z, bb.w); u0.w = *(unsigned*)&hh;
    hh = __floats2half2_rn(c.x, c.y);   u1.x = *(unsigned*)&hh;
    hh = __floats2half2_rn(c.z, c.w);   u1.y = *(unsigned*)&hh;
    hh = __floats2half2_rn(d.x, d.y);   u1.z = *(unsigned*)&hh;
    hh = __floats2half2_rn(d.z, d.w);   u1.w = *(unsigned*)&hh;
    int pos = atomicAdd(&cur[dst >> 8], 1);
    s_tmp[pos] = make_int2(src | ((dst & 255) << 16), e);
    ea_tmp[(size_t)pos * 2]     = u0;
    ea_tmp[(size_t)pos * 2 + 1] = u1;
  }
}

// one block per bucket -> exact CSR (offs + s_se{src,eid} + s_ea)
__global__ __launch_bounds__(256) void fine_csr_kernel(
    const int2* __restrict__ s_tmp, const uint4* __restrict__ ea_tmp,
    const int* __restrict__ coarse_offs,
    int2* __restrict__ s_se, uint4* __restrict__ s_ea4,
    int* __restrict__ offs) {
  __shared__ int cnt[256], sc[256], cur[256];
  int t = threadIdx.x, b = blockIdx.x;
  int lo = coarse_offs[b], hi = coarse_offs[b + 1];
  cnt[t] = 0;
  __syncthreads();
  for (int p = lo + t; p < hi; p += 256)
    atomicAdd(&cnt[(s_tmp[p].x >> 16) & 255], 1);
  __syncthreads();
  int myc = cnt[t];
  sc[t] = myc;
  __syncthreads();
  for (int d = 1; d < 256; d <<= 1) {
    int v = (t >= d) ? sc[t - d] : 0;
    __syncthreads();
    sc[t] += v;
    __syncthreads();
  }
  int excl = sc[t] - myc;
  cur[t] = lo + excl;
  int gd = b * 256 + t;
  if (gd <= NN) offs[gd] = lo + excl;
  __syncthreads();
  for (int p = lo + t; p < hi; p += 256) {
    int2 m = s_tmp[p];
    uint4 u0 = ea_tmp[(size_t)p * 2];
    uint4 u1 = ea_tmp[(size_t)p * 2 + 1];
    int pos = atomicAdd(&cur[(m.x >> 16) & 255], 1);
    s_se[pos] = make_int2(m.x & 0xFFFF, m.y);
    s_ea4[(size_t)pos * 2]     = u0;
    s_ea4[(size_t)pos * 2 + 1] = u1;
  }
}

// ---------------- Kernel 3: aggregation + A/C epilogue -----------------
// one wave per dst node; lane = (e1, h, p): e1 = edge-of-pair half,
// h = head, p = element-pair slot. Each VMEM/VALU instruction covers 2
// edges; float2/half2 element packing; 8 edges in flight (4 pairs).
__global__ __launch_bounds__(256) void aggregate_kernel(
    const float* __restrict__ y, const float* __restrict__ qe,
    const float* __restrict__ u4, const float* __restrict__ w4,
    const float* __restrict__ x, const __half* __restrict__ s_ea,
    const int2* __restrict__ s_se,
    const float* __restrict__ We, const float* __restrict__ Wv,
    const float* __restrict__ bv,
    const float* __restrict__ Wskip, const float* __restrict__ bskip,
    const float* __restrict__ W1, const float* __restrict__ b1,
    const int* __restrict__ offs,
    __half* __restrict__ Ah, __half* __restrict__ Cbh) {
  int wave = threadIdx.x >> 6, lane = threadIdx.x & 63;
  int n = blockIdx.x * 4 + wave;
  int e1 = lane >> 5;          // 0/1: which edge of the pair
  int h  = (lane >> 3) & 3;    // head
  int p  = lane & 7;           // element pair slot (elements 2p, 2p+1)

  float2 y2 = ((const float2*)(y + n * 64 + h * 16))[p];
  float2 q2 = ((const float2*)(qe + n * 64 + h * 16))[p];
  float u_n = u4[n * 4 + h];
  int off = offs[n], end = offs[n + 1];

  float s = 0.f, ax0 = 0.f, ax1 = 0.f, ae0 = 0.f, ae1 = 0.f;

  int j = off;
  for (; j + 8 <= end; j += 8) {   // 4 pairs = 8 edges in flight
    int src[4];
#pragma unroll
    for (int u = 0; u < 4; u++) src[u] = s_se[j + 2 * u + e1].x;
    float2 xv[4], ev[4];
    float wv4[4];
#pragma unroll
    for (int u = 0; u < 4; u++) {
      int jd = j + 2 * u + e1;
      xv[u] = ((const float2*)(x + (size_t)src[u] * 16))[p];
      ev[u] = __half22float2(*(const __half2*)(s_ea + (size_t)jd * 16 + 2 * p));
      wv4[u] = w4[(unsigned)src[u] * 4u + (unsigned)h];
    }
    float pp[4];
#pragma unroll
    for (int u = 0; u < 4; u++)
      pp[u] = xv[u].x * y2.x + xv[u].y * y2.y + ev[u].x * q2.x + ev[u].y * q2.y;
#pragma unroll
    for (int d = 1; d < 8; d <<= 1) {
#pragma unroll
      for (int u = 0; u < 4; u++) pp[u] += __shfl_xor(pp[u], d);
    }
#pragma unroll
    for (int u = 0; u < 4; u++) {
      float wgt = exp2f(pp[u] + u_n + wv4[u]);
      s += wgt;
      ax0 = fmaf(wgt, xv[u].x, ax0); ax1 = fmaf(wgt, xv[u].y, ax1);
      ae0 = fmaf(wgt, ev[u].x, ae0); ae1 = fmaf(wgt, ev[u].y, ae1);
    }
  }
  for (; j + 2 <= end; j += 2) {   // pair tail
    int jd = j + e1;
    int src = s_se[jd].x;
    float2 xv = ((const float2*)(x + (size_t)src * 16))[p];
    float2 ev = __half22float2(*(const __half2*)(s_ea + (size_t)jd * 16 + 2 * p));
    float wv_ = w4[(unsigned)src * 4u + (unsigned)h];
    float pp = xv.x * y2.x + xv.y * y2.y + ev.x * q2.x + ev.y * q2.y;
    pp += __shfl_xor(pp, 1); pp += __shfl_xor(pp, 2); pp += __shfl_xor(pp, 4);
    float wgt = exp2f(pp + u_n + wv_);
    s += wgt;
    ax0 = fmaf(wgt, xv.x, ax0); ax1 = fmaf(wgt, xv.y, ax1);
    ae0 = fmaf(wgt, ev.x, ae0); ae1 = fmaf(wgt, ev.y, ae1);
  }
  if (j < end) {                   // single tail (predicated: e1==0 only)
    int src = s_se[j].x;
    float2 xv = ((const float2*)(x + (size_t)src * 16))[p];
    float2 ev = __half22float2(*(const __half2*)(s_ea + (size_t)j * 16 + 2 * p));
    float wv_ = w4[(unsigned)src * 4u + (unsigned)h];
    float pp = xv.x * y2.x + xv.y * y2.y + ev.x * q2.x + ev.y * q2.y;
    pp += __shfl_xor(pp, 1); pp += __shfl_xor(pp, 2); pp += __shfl_xor(pp, 4);
    float wgt = (e1 == 0) ? exp2f(pp + u_n + wv_) : 0.f;
    s += wgt;
    ax0 = fmaf(wgt, xv.x, ax0); ax1 = fmaf(wgt, xv.y, ax1);
    ae0 = fmaf(wgt, ev.x, ae0); ae1 = fmaf(wgt, ev.y, ae1);
  }

  // cross-half reduce (both e1 halves hold partial sums of the same node)
  s   += __shfl_xor(s, 32);
  ax0 += __shfl_xor(ax0, 32); ax1 += __shfl_xor(ax1, 32);
  ae0 += __shfl_xor(ae0, 32); ae1 += __shfl_xor(ae1, 32);

  float inv = (end > off) ? 1.f / s : 0.f;
  float dflag = (end > off) ? 1.f : 0.f;
  float an0 = ax0 * inv, an1 = ax1 * inv;
  float en0 = ae0 * inv, en1 = ae1 * inv;

  // epilogue: lane output channel t_out = e1*8 + p (0..15) within head h
  int t_out = (e1 << 3) | p;
  int base = h * 32 + t_out;
  int hb = lane & 24;  // h<<3

  float r0 = dflag * bv[base], r1 = dflag * bv[base + 16];
#pragma unroll
  for (int i = 0; i < 16; i++) {
    float axi = __shfl((i & 1) ? an1 : an0, hb | (i >> 1));
    float aei = __shfl((i & 1) ? en1 : en0, hb | (i >> 1));
    r0 += axi * Wv[i * 128 + base]      + aei * We[i * 128 + base];
    r1 += axi * Wv[i * 128 + base + 16] + aei * We[i * 128 + base + 16];
  }
  // mean over heads (head index lives in bits 3-4)
  r0 += __shfl_xor(r0, 8); r0 += __shfl_xor(r0, 16);
  r1 += __shfl_xor(r1, 8); r1 += __shfl_xor(r1, 16);

  // skip connection
  float sk0 = bskip[t_out], sk1 = bskip[t_out + 16];
#pragma unroll
  for (int i = 0; i < 16; i++) {
    float xi = x[n * 16 + i];
    sk0 += xi * Wskip[i * 32 + t_out];
    sk1 += xi * Wskip[i * 32 + t_out + 16];
  }
  float o0 = 0.25f * r0 + sk0;  // out[n][t_out]
  float o1 = 0.25f * r1 + sk1;  // out[n][t_out+16]

  // A[n][jj] = out@W1[0:32]; Cb[n][jj] = out@W1[48:80] + b1  (stored f16)
  // out channel i (o0 side) is held by lane ((i&8)<<2)|(i&7)  (h=0, e1=i>>3)
  int jj = lane & 31;
  int roff = (lane < 32) ? 0 : 48;
  float acc = (lane < 32) ? 0.f : b1[jj];
#pragma unroll
  for (int i = 0; i < 16; i++) {
    float oi = __shfl(o0, ((i & 8) << 2) | (i & 7));
    acc += oi * W1[(roff + i) * 32 + jj];
  }
#pragma unroll
  for (int i = 0; i < 16; i++) {
    float oi = __shfl(o1, ((i & 8) << 2) | (i & 7));
    acc += oi * W1[(roff + 16 + i) * 32 + jj];
  }
  float nb = __shfl_xor(acc, 1);
  if ((lane & 1) == 0) {
    __half2 hh = __floats2half2_rn(acc, nb);
    if (lane < 32) *(__half2*)(Ah  + n * 32 + jj) = hh;
    else           *(__half2*)(Cbh + n * 32 + jj) = hh;
  }
}

// ---------------- Kernel 4: per-edge MLP, CSR order --------------------
// wave per dst node, 2 edges per iter. Cb invariant, s_ea sequential f16,
// A f16 gather (64B/row), W1e/W2 columns in registers, out[eid] scatter.
__global__ __launch_bounds__(256) void mlp_kernel(
    const int2* __restrict__ s_se, const __half* __restrict__ s_ea,
    const int* __restrict__ offs,
    const __half* __restrict__ Ah, const __half* __restrict__ Cbh,
    const float* __restrict__ W1, const float* __restrict__ W2,
    const float* __restrict__ b2v, float* __restrict__ out) {
  int wave = threadIdx.x >> 6, lane = threadIdx.x & 63;
  int n = blockIdx.x * 4 + wave;
  int g = lane >> 5, l = lane & 31;

  float w1e[16];
#pragma unroll
  for (int i = 0; i < 16; i++) w1e[i] = W1[(32 + i) * 32 + l];
  float w2j = W2[l];
  float b2s = b2v[0];
  float cb = __half2float(Cbh[n * 32 + l]);
  int off = offs[n], end = offs[n + 1];

  for (int p = off + g; p < end; p += 2) {
    int2 se = s_se[p];
    float a = __half2float(Ah[(unsigned)se.x * 32u + l]);
    const uint4* eap = (const uint4*)(s_ea + (size_t)p * 16);
    uint4 u0 = eap[0], u1 = eap[1];
    float hsum = a + cb;
    const __half2* hp0 = (const __half2*)&u0;
    const __half2* hp1 = (const __half2*)&u1;
#pragma unroll
    for (int i = 0; i < 4; i++) {
      float2 f0 = __half22float2(hp0[i]);
      hsum += f0.x * w1e[2 * i] + f0.y * w1e[2 * i + 1];
      float2 f1 = __half22float2(hp1[i]);
      hsum += f1.x * w1e[8 + 2 * i] + f1.y * w1e[8 + 2 * i + 1];
    }
    float hv = fmaxf(hsum, 0.f) * w2j;
    hv += __shfl_xor(hv, 1); hv += __shfl_xor(hv, 2);
    hv += __shfl_xor(hv, 4); hv += __shfl_xor(hv, 8);
    hv += __shfl_xor(hv, 16);
    if (l == 0) out[se.y] = hv + b2s;
  }
}

// ---------------- launch -----------------------------------------------
extern "C" void kernel_launch(void* const* d_in, const int* in_sizes, int n_in,
                              void* d_out, int out_size, void* d_ws, size_t ws_size,
                              hipStream_t stream) {
  const float* x         = (const float*)d_in[0];
  const int*   ei        = (const int*)d_in[1];
  const float* edge_attr = (const float*)d_in[2];
  const float* Wq = (const float*)d_in[3],  *bq = (const float*)d_in[4];
  const float* Wk = (const float*)d_in[5],  *bk = (const float*)d_in[6];
  const float* Wv = (const float*)d_in[7],  *bv = (const float*)d_in[8];
  const float* We = (const float*)d_in[9];
  const float* Wskip = (const float*)d_in[10], *bskip = (const float*)d_in[11];
  const float* W1 = (const float*)d_in[12], *b1 = (const float*)d_in[13];
  const float* W2 = (const float*)d_in[14], *b2 = (const float*)d_in[15];
  float* out = (float*)d_out;

  // workspace layout (~91.7 MB); Ah/Cbh ALIAS ea_tmp (dead after fine_csr)
  char* w = (char*)d_ws;
  float*   y    = (float*)w;            w += (size_t)NN * 64 * 4;   // 12.8 MB
  float*   qe   = (float*)w;            w += (size_t)NN * 64 * 4;   // 12.8 MB
  float*   u4   = (float*)w;            w += (size_t)NN * 4 * 4;    // 0.8 MB
  float*   w4   = (float*)w;            w += (size_t)NN * 4 * 4;    // 0.8 MB
  int2*    s_se = (int2*)w;             w += (size_t)NE * 8;        // 6.4 MB
  int2*    s_tmp = (int2*)w;            w += (size_t)NE * 8;        // 6.4 MB
  uint4*   s_ea4 = (uint4*)w;           w += (size_t)NE * 32;       // 25.6 MB
  uint4*   ea_tmp = (uint4*)w;          // 25.6 MB (Ah, Cbh alias inside)
  __half*  Ah   = (__half*)ea_tmp;                          // 3.2 MB
  __half*  Cbh  = (__half*)((char*)ea_tmp + (size_t)NN * 32 * 2); // 3.2 MB
  w += (size_t)NE * 32;
  int*     hist_all = (int*)w;          w += (size_t)256 * 256 * 4; // 256 KB
  int*     btot = (int*)w;              w += 256 * 4;
  int*     coarse_offs = (int*)w;       w += 256 * 4;
  int*     offs = (int*)w;              w += ((size_t)NN + 1) * 4;
  float*   Mbuf = (float*)w;            w += 1056 * 4;

  precompute_kernel<<<1, 256, 0, stream>>>(Wq, Wk, bq, bk, Mbuf);
  node_linear_kernel<<<NODE_BLOCKS + 256, 256, 0, stream>>>(
      x, Wq, bq, Wk, bk, We, Mbuf, ei, hist_all, y, qe, u4, w4);
  scan_buckets_kernel<<<49, 256, 0, stream>>>(hist_all, btot);
  tiny_scan_kernel<<<1, 256, 0, stream>>>(btot, coarse_offs);
  bucket_scatter_kernel<<<256, 256, 0, stream>>>(ei, edge_attr, hist_all,
                                                 coarse_offs, s_tmp, ea_tmp);
  fine_csr_kernel<<<NB, 256, 0, stream>>>(s_tmp, ea_tmp, coarse_offs,
                                          s_se, s_ea4, offs);
  aggregate_kernel<<<NN / 4, 256, 0, stream>>>(y, qe, u4, w4, x,
                                               (const __half*)s_ea4, s_se,
                                               We, Wv, bv, Wskip, bskip, W1, b1,
                                               offs, Ah, Cbh);
  mlp_kernel<<<NN / 4, 256, 0, stream>>>(s_se, (const __half*)s_ea4, offs,
                                         Ah, Cbh, W1, W2, b2, out);
}

// Round 12
// 303.521 us; speedup vs baseline: 1.0689x; 1.0689x over previous
//
#include <hip/hip_runtime.h>
#include <hip/hip_fp16.h>

#define NN 50000
#define NE 800000
// IN_C=16, EDGE_IN=16, HID=32, HEADS=4, HC=128
#define NB 196            // coarse buckets = ceil(NN/256)
#define EPB 3125          // edges per bucket-build block (NE/256)
#define NODE_BLOCKS 12500 // NN/4

// scale folded into all alpha components: log2(e)/sqrt(32)
#define SL 0.25506413f

// DPP-based add over lanes: quad xor1=0xB1, xor2=0x4E, row_ror:4=0x124,
// row_ror:8=0x128 (rows are 16 lanes = one head group). VALU-pipe only.
template <int CTRL>
__device__ __forceinline__ float dpp_add(float v) {
  int m = __builtin_amdgcn_update_dpp(0, __builtin_bit_cast(int, v), CTRL, 0xF, 0xF, true);
  return v + __builtin_bit_cast(float, m);
}
__device__ __forceinline__ float row16_reduce(float v) {
  v = dpp_add<0xB1>(v);   // + xor1
  v = dpp_add<0x4E>(v);   // + xor2  -> quad sums
  v = dpp_add<0x124>(v);  // + ror4  -> two quads
  v = dpp_add<0x128>(v);  // + ror8  -> all four quads
  return v;
}

// ---------------- Kernel 0: weight precompute --------------------------
__global__ __launch_bounds__(256) void precompute_kernel(
    const float* __restrict__ Wq, const float* __restrict__ Wk,
    const float* __restrict__ bq, const float* __restrict__ bk,
    float* __restrict__ Mbuf) {
  int t = threadIdx.x;
  for (int idx = t; idx < 1024; idx += 256) {
    int h = idx >> 8, i = (idx >> 4) & 15, j = idx & 15;
    float acc = 0.f;
#pragma unroll
    for (int c = 0; c < 32; c++)
      acc += Wq[i * 128 + h * 32 + c] * Wk[j * 128 + h * 32 + c];
    Mbuf[idx] = acc * SL;
  }
  if (t < 4) {
    float acc = 0.f;
#pragma unroll
    for (int c = 0; c < 32; c++) acc += bq[t * 32 + c] * bk[t * 32 + c];
    Mbuf[1024 + t] = acc * SL;
  }
}

// ---------------- Kernel 1: node precompute + coarse hist (fused) ------
__global__ __launch_bounds__(256) void node_linear_kernel(
    const float* __restrict__ x,
    const float* __restrict__ Wq, const float* __restrict__ bq,
    const float* __restrict__ Wk, const float* __restrict__ bk,
    const float* __restrict__ We, const float* __restrict__ Mbuf,
    const int* __restrict__ ei, int* __restrict__ hist_all,
    float* __restrict__ y, float* __restrict__ qe,
    float* __restrict__ u4, float* __restrict__ w4) {
  __shared__ int hist[NB];
  if (blockIdx.x >= NODE_BLOCKS) {
    int b = blockIdx.x - NODE_BLOCKS;  // [0,256)
    int t = threadIdx.x;
    if (t < NB) hist[t] = 0;
    __syncthreads();
    int base = b * EPB;
    for (int i = t; i < EPB; i += 256)
      atomicAdd(&hist[ei[NE + base + i] >> 8], 1);
    __syncthreads();
    if (t < NB) hist_all[t * 256 + b] = hist[t];
    return;
  }
  int wave = threadIdx.x >> 6;
  int lane = threadIdx.x & 63;
  int n = blockIdx.x * 4 + wave;
  int h = lane >> 4, t = lane & 15, base = h * 32 + t;
  int gb = lane & 48;

  float xr[16];
#pragma unroll
  for (int i = 0; i < 16; i++) xr[i] = x[n * 16 + i];

  float bqb = bq[base], bq16 = bq[base + 16];
  float bkb = bk[base], bk16 = bk[base + 16];
  float qb = bqb, q16 = bq16;
  float kb = bkb, k16 = bk16;
#pragma unroll
  for (int i = 0; i < 16; i++) {
    qb  += xr[i] * Wq[i * 128 + base];
    q16 += xr[i] * Wq[i * 128 + base + 16];
    kb  += xr[i] * Wk[i * 128 + base];
    k16 += xr[i] * Wk[i * 128 + base + 16];
  }

  // y_ht = sum_i x_i * M[h][i][t]  (M pre-scaled by SL)
  float yt = 0.f;
#pragma unroll
  for (int i = 0; i < 16; i++) yt += xr[i] * Mbuf[h * 256 + i * 16 + t];
  y[n * 64 + lane] = yt;

  // qe[h][t] = SL * sum_c q[h*32+c] * We[t*128 + h*32 + c]
  float acc = 0.f;
#pragma unroll
  for (int i = 0; i < 16; i++) {
    float qv  = __shfl(qb,  gb | i);
    float qv2 = __shfl(q16, gb | i);
    acc += qv * We[t * 128 + h * 32 + i] + qv2 * We[t * 128 + h * 32 + 16 + i];
  }
  qe[n * 64 + lane] = acc * SL;

  // u_h = SL*(q_h . bk_h) - SL*(bq_h . bk_h);  w_h = SL*(bq_h . k_h)
  float pu = qb * bkb + q16 * bk16;
  float pw = bqb * kb + bq16 * k16;
  pu += __shfl_xor(pu, 1); pw += __shfl_xor(pw, 1);
  pu += __shfl_xor(pu, 2); pw += __shfl_xor(pw, 2);
  pu += __shfl_xor(pu, 4); pw += __shfl_xor(pw, 4);
  pu += __shfl_xor(pu, 8); pw += __shfl_xor(pw, 8);
  if (t == 0) {
    u4[n * 4 + h] = pu * SL - Mbuf[1024 + h];
    w4[n * 4 + h] = pw * SL;
  }
}

// ---------------- CSR build ---------------------------------------------
__global__ __launch_bounds__(256) void scan_buckets_kernel(
    int* __restrict__ hist_all, int* __restrict__ btot) {
  int wv = blockIdx.x * 4 + (threadIdx.x >> 6);
  int l = threadIdx.x & 63;
  if (wv >= NB) return;
  int base = wv * 256;
  int run = 0;
#pragma unroll
  for (int c = 0; c < 4; c++) {
    int v = hist_all[base + c * 64 + l];
    int orig = v;
#pragma unroll
    for (int d = 1; d < 64; d <<= 1) {
      int u = __shfl_up(v, d);
      if (l >= d) v += u;
    }
    hist_all[base + c * 64 + l] = run + v - orig;
    run += __shfl(v, 63);
  }
  if (l == 0) btot[wv] = run;
}

__global__ __launch_bounds__(256) void tiny_scan_kernel(
    const int* __restrict__ btot, int* __restrict__ coarse_offs) {
  __shared__ int sc[256];
  int t = threadIdx.x;
  int v = (t < NB) ? btot[t] : 0;
  sc[t] = v;
  __syncthreads();
  for (int d = 1; d < 256; d <<= 1) {
    int u = (t >= d) ? sc[t - d] : 0;
    __syncthreads();
    sc[t] += u;
    __syncthreads();
  }
  if (t < NB) coarse_offs[t] = sc[t] - v;
  if (t == NB - 1) coarse_offs[NB] = sc[t];
}

// scatter edges into coarse-bucket order, carrying {src,eid} + ea f16
__global__ __launch_bounds__(256) void bucket_scatter_kernel(
    const int* __restrict__ ei, const float* __restrict__ edge_attr,
    const int* __restrict__ cursor_all, const int* __restrict__ coarse_offs,
    int2* __restrict__ s_tmp, uint4* __restrict__ ea_tmp) {
  __shared__ int cur[NB];
  int t = threadIdx.x, b = blockIdx.x;
  if (t < NB) cur[t] = cursor_all[t * 256 + b] + coarse_offs[t];
  __syncthreads();
  int base = b * EPB;
  for (int i = t; i < EPB; i += 256) {
    int e = base + i;
    int src = ei[e], dst = ei[NE + e];
    const float4* eap = (const float4*)(edge_attr + (size_t)e * 16);
    float4 a = eap[0], bb = eap[1], c = eap[2], d = eap[3];
    uint4 u0, u1;
    __half2 hh;
    hh = __floats2half2_rn(a.x, a.y);   u0.x = *(unsigned*)&hh;
    hh = __floats2half2_rn(a.z, a.w);   u0.y = *(unsigned*)&hh;
    hh = __floats2half2_rn(bb.x, bb.y); u0.z = *(unsigned*)&hh;
    hh = __floats2half2_rn(bb.z, bb.w); u0.w = *(unsigned*)&hh;
    hh = __floats2half2_rn(c.x, c.y);   u1.x = *(unsigned*)&hh;
    hh = __floats2half2_rn(c.z, c.w);   u1.y = *(unsigned*)&hh;
    hh = __floats2half2_rn(d.x, d.y);   u1.z = *(unsigned*)&hh;
    hh = __floats2half2_rn(d.z, d.w);   u1.w = *(unsigned*)&hh;
    int pos = atomicAdd(&cur[dst >> 8], 1);
    s_tmp[pos] = make_int2(src | ((dst & 255) << 16), e);
    ea_tmp[(size_t)pos * 2]     = u0;
    ea_tmp[(size_t)pos * 2 + 1] = u1;
  }
}

// one block per bucket -> exact CSR (offs + s_se{src,eid} + s_ea)
__global__ __launch_bounds__(256) void fine_csr_kernel(
    const int2* __restrict__ s_tmp, const uint4* __restrict__ ea_tmp,
    const int* __restrict__ coarse_offs,
    int2* __restrict__ s_se, uint4* __restrict__ s_ea4,
    int* __restrict__ offs) {
  __shared__ int cnt[256], sc[256], cur[256];
  int t = threadIdx.x, b = blockIdx.x;
  int lo = coarse_offs[b], hi = coarse_offs[b + 1];
  cnt[t] = 0;
  __syncthreads();
  for (int p = lo + t; p < hi; p += 256)
    atomicAdd(&cnt[(s_tmp[p].x >> 16) & 255], 1);
  __syncthreads();
  int myc = cnt[t];
  sc[t] = myc;
  __syncthreads();
  for (int d = 1; d < 256; d <<= 1) {
    int v = (t >= d) ? sc[t - d] : 0;
    __syncthreads();
    sc[t] += v;
    __syncthreads();
  }
  int excl = sc[t] - myc;
  cur[t] = lo + excl;
  int gd = b * 256 + t;
  if (gd <= NN) offs[gd] = lo + excl;
  __syncthreads();
  for (int p = lo + t; p < hi; p += 256) {
    int2 m = s_tmp[p];
    uint4 u0 = ea_tmp[(size_t)p * 2];
    uint4 u1 = ea_tmp[(size_t)p * 2 + 1];
    int pos = atomicAdd(&cur[(m.x >> 16) & 255], 1);
    s_se[pos] = make_int2(m.x & 0xFFFF, m.y);
    s_ea4[(size_t)pos * 2]     = u0;
    s_ea4[(size_t)pos * 2 + 1] = u1;
  }
}

// ---------------- Kernel 3: aggregation + A/C epilogue -----------------
// one wave per dst node; 16 lanes/head (R10 layout); sequential s_se/s_ea;
// 8-edge ILP; dot reduce via DPP (VALU pipe, zero DS ops in loop).
__global__ __launch_bounds__(256) void aggregate_kernel(
    const float* __restrict__ y, const float* __restrict__ qe,
    const float* __restrict__ u4, const float* __restrict__ w4,
    const float* __restrict__ x, const __half* __restrict__ s_ea,
    const int2* __restrict__ s_se,
    const float* __restrict__ We, const float* __restrict__ Wv,
    const float* __restrict__ bv,
    const float* __restrict__ Wskip, const float* __restrict__ bskip,
    const float* __restrict__ W1, const float* __restrict__ b1,
    const int* __restrict__ offs,
    __half* __restrict__ Ah, __half* __restrict__ Cbh) {
  int wave = threadIdx.x >> 6, lane = threadIdx.x & 63;
  int n = blockIdx.x * 4 + wave;
  int h = lane >> 4, t = lane & 15;
  int base = h * 32 + t;
  int gb = lane & 48;

  float yt = y[n * 64 + lane];
  float qet = qe[n * 64 + lane];
  float u_n = u4[n * 4 + h];
  int off = offs[n], end = offs[n + 1];

  float s = 0.f, ax = 0.f, ae = 0.f;
  int j = off;
  for (; j + 8 <= end; j += 8) {
    const uint4* sp = (const uint4*)&s_se[j];
    uint4 sa = sp[0], sb = sp[1], sc4 = sp[2], sd = sp[3];
    int src[8] = {(int)sa.x, (int)sa.z, (int)sb.x, (int)sb.z,
                  (int)sc4.x, (int)sc4.z, (int)sd.x, (int)sd.z};
    float xs[8], ea[8], uw[8];
#pragma unroll
    for (int u = 0; u < 8; u++) {
      xs[u] = x[(unsigned)src[u] * 16u + (unsigned)t];
      ea[u] = __half2float(s_ea[(size_t)(j + u) * 16 + t]);
      uw[u] = w4[(unsigned)src[u] * 4u + (unsigned)h];
    }
    float p[8];
#pragma unroll
    for (int u = 0; u < 8; u++) p[u] = fmaf(yt, xs[u], qet * ea[u]);
#pragma unroll
    for (int u = 0; u < 8; u++) p[u] = row16_reduce(p[u]);
#pragma unroll
    for (int u = 0; u < 8; u++) {
      float wgt = exp2f(p[u] + u_n + uw[u]);
      s += wgt;
      ax = fmaf(wgt, xs[u], ax);
      ae = fmaf(wgt, ea[u], ae);
    }
  }
  for (; j < end; j++) {
    int srcu = s_se[j].x;
    float xs = x[(unsigned)srcu * 16u + (unsigned)t];
    float ea_ = __half2float(s_ea[(size_t)j * 16 + t]);
    float uw = w4[(unsigned)srcu * 4u + (unsigned)h];
    float p = fmaf(yt, xs, qet * ea_);
    p = row16_reduce(p);
    float wgt = exp2f(p + u_n + uw);
    s += wgt;
    ax = fmaf(wgt, xs, ax);
    ae = fmaf(wgt, ea_, ae);
  }

  float inv = (end > off) ? 1.f / s : 0.f;
  float dflag = (end > off) ? 1.f : 0.f;
  float axn = ax * inv, aen = ae * inv;
  float r0 = dflag * bv[base], r1 = dflag * bv[base + 16];
#pragma unroll
  for (int i = 0; i < 16; i++) {
    float axi = __shfl(axn, gb | i);
    float aei = __shfl(aen, gb | i);
    r0 += axi * Wv[i * 128 + base]      + aei * We[i * 128 + base];
    r1 += axi * Wv[i * 128 + base + 16] + aei * We[i * 128 + base + 16];
  }
  // mean over heads
  r0 += __shfl_xor(r0, 16); r0 += __shfl_xor(r0, 32);
  r1 += __shfl_xor(r1, 16); r1 += __shfl_xor(r1, 32);

  // skip connection
  float sk0 = bskip[t], sk1 = bskip[t + 16];
#pragma unroll
  for (int i = 0; i < 16; i++) {
    float xi = x[n * 16 + i];
    sk0 += xi * Wskip[i * 32 + t];
    sk1 += xi * Wskip[i * 32 + t + 16];
  }
  float o0 = 0.25f * r0 + sk0;  // out[n][t]
  float o1 = 0.25f * r1 + sk1;  // out[n][t+16]

  // A[n][jj] = out@W1[0:32]; Cb[n][jj] = out@W1[48:80] + b1  (stored f16)
  int jj = lane & 31;
  int roff = (lane < 32) ? 0 : 48;
  float acc = (lane < 32) ? 0.f : b1[jj];
#pragma unroll
  for (int i = 0; i < 16; i++) {
    float oi = __shfl(o0, i);
    acc += oi * W1[(roff + i) * 32 + jj];
  }
#pragma unroll
  for (int i = 0; i < 16; i++) {
    float oi = __shfl(o1, i);
    acc += oi * W1[(roff + 16 + i) * 32 + jj];
  }
  float nb = __shfl_xor(acc, 1);
  if ((lane & 1) == 0) {
    __half2 hh = __floats2half2_rn(acc, nb);
    if (lane < 32) *(__half2*)(Ah  + n * 32 + jj) = hh;
    else           *(__half2*)(Cbh + n * 32 + jj) = hh;
  }
}

// ---------------- Kernel 4: per-edge MLP, CSR order --------------------
// wave per dst node, 2 edges per iter. Cb invariant (f16), s_ea sequential
// f16, A f16 gather (64B/row), W1e/W2 columns in registers.
__global__ __launch_bounds__(256) void mlp_kernel(
    const int2* __restrict__ s_se, const __half* __restrict__ s_ea,
    const int* __restrict__ offs,
    const __half* __restrict__ Ah, const __half* __restrict__ Cbh,
    const float* __restrict__ W1, const float* __restrict__ W2,
    const float* __restrict__ b2v, float* __restrict__ out) {
  int wave = threadIdx.x >> 6, lane = threadIdx.x & 63;
  int n = blockIdx.x * 4 + wave;
  int g = lane >> 5, l = lane & 31;

  float w1e[16];
#pragma unroll
  for (int i = 0; i < 16; i++) w1e[i] = W1[(32 + i) * 32 + l];
  float w2j = W2[l];
  float b2s = b2v[0];
  float cb = __half2float(Cbh[n * 32 + l]);
  int off = offs[n], end = offs[n + 1];

  for (int p = off + g; p < end; p += 2) {
    int2 se = s_se[p];
    float a = __half2float(Ah[(unsigned)se.x * 32u + l]);
    const uint4* eap = (const uint4*)(s_ea + (size_t)p * 16);
    uint4 u0 = eap[0], u1 = eap[1];
    float hsum = a + cb;
    const __half2* hp0 = (const __half2*)&u0;
    const __half2* hp1 = (const __half2*)&u1;
#pragma unroll
    for (int i = 0; i < 4; i++) {
      float2 f0 = __half22float2(hp0[i]);
      hsum += f0.x * w1e[2 * i] + f0.y * w1e[2 * i + 1];
      float2 f1 = __half22float2(hp1[i]);
      hsum += f1.x * w1e[8 + 2 * i] + f1.y * w1e[8 + 2 * i + 1];
    }
    float hv = fmaxf(hsum, 0.f) * w2j;
    hv += __shfl_xor(hv, 1); hv += __shfl_xor(hv, 2);
    hv += __shfl_xor(hv, 4); hv += __shfl_xor(hv, 8);
    hv += __shfl_xor(hv, 16);
    if (l == 0) out[se.y] = hv + b2s;
  }
}

// ---------------- launch -----------------------------------------------
extern "C" void kernel_launch(void* const* d_in, const int* in_sizes, int n_in,
                              void* d_out, int out_size, void* d_ws, size_t ws_size,
                              hipStream_t stream) {
  const float* x         = (const float*)d_in[0];
  const int*   ei        = (const int*)d_in[1];
  const float* edge_attr = (const float*)d_in[2];
  const float* Wq = (const float*)d_in[3],  *bq = (const float*)d_in[4];
  const float* Wk = (const float*)d_in[5],  *bk = (const float*)d_in[6];
  const float* Wv = (const float*)d_in[7],  *bv = (const float*)d_in[8];
  const float* We = (const float*)d_in[9];
  const float* Wskip = (const float*)d_in[10], *bskip = (const float*)d_in[11];
  const float* W1 = (const float*)d_in[12], *b1 = (const float*)d_in[13];
  const float* W2 = (const float*)d_in[14], *b2 = (const float*)d_in[15];
  float* out = (float*)d_out;

  // workspace layout (~91.7 MB); Ah/Cbh ALIAS ea_tmp (dead after fine_csr)
  char* w = (char*)d_ws;
  float*   y    = (float*)w;            w += (size_t)NN * 64 * 4;   // 12.8 MB
  float*   qe   = (float*)w;            w += (size_t)NN * 64 * 4;   // 12.8 MB
  float*   u4   = (float*)w;            w += (size_t)NN * 4 * 4;    // 0.8 MB
  float*   w4   = (float*)w;            w += (size_t)NN * 4 * 4;    // 0.8 MB
  int2*    s_se = (int2*)w;             w += (size_t)NE * 8;        // 6.4 MB
  int2*    s_tmp = (int2*)w;            w += (size_t)NE * 8;        // 6.4 MB
  uint4*   s_ea4 = (uint4*)w;           w += (size_t)NE * 32;       // 25.6 MB
  uint4*   ea_tmp = (uint4*)w;          // 25.6 MB (Ah, Cbh alias inside)
  __half*  Ah   = (__half*)ea_tmp;                          // 3.2 MB
  __half*  Cbh  = (__half*)((char*)ea_tmp + (size_t)NN * 32 * 2); // 3.2 MB
  w += (size_t)NE * 32;
  int*     hist_all = (int*)w;          w += (size_t)256 * 256 * 4; // 256 KB
  int*     btot = (int*)w;              w += 256 * 4;
  int*     coarse_offs = (int*)w;       w += 256 * 4;
  int*     offs = (int*)w;              w += ((size_t)NN + 1) * 4;
  float*   Mbuf = (float*)w;            w += 1056 * 4;

  precompute_kernel<<<1, 256, 0, stream>>>(Wq, Wk, bq, bk, Mbuf);
  node_linear_kernel<<<NODE_BLOCKS + 256, 256, 0, stream>>>(
      x, Wq, bq, Wk, bk, We, Mbuf, ei, hist_all, y, qe, u4, w4);
  scan_buckets_kernel<<<49, 256, 0, stream>>>(hist_all, btot);
  tiny_scan_kernel<<<1, 256, 0, stream>>>(btot, coarse_offs);
  bucket_scatter_kernel<<<256, 256, 0, stream>>>(ei, edge_attr, hist_all,
                                                 coarse_offs, s_tmp, ea_tmp);
  fine_csr_kernel<<<NB, 256, 0, stream>>>(s_tmp, ea_tmp, coarse_offs,
                                          s_se, s_ea4, offs);
  aggregate_kernel<<<NN / 4, 256, 0, stream>>>(y, qe, u4, w4, x,
                                               (const __half*)s_ea4, s_se,
                                               We, Wv, bv, Wskip, bskip, W1, b1,
                                               offs, Ah, Cbh);
  mlp_kernel<<<NN / 4, 256, 0, stream>>>(s_se, (const __half*)s_ea4, offs,
                                         Ah, Cbh, W1, W2, b2, out);
}

// Round 13
// 259.535 us; speedup vs baseline: 1.2501x; 1.1695x over previous
//
#include <hip/hip_runtime.h>
#include <hip/hip_fp16.h>

#define NN 50000
#define NE 800000
// IN_C=16, EDGE_IN=16, HID=32, HEADS=4, HC=128
#define NB 196            // coarse buckets = ceil(NN/256)
#define EPB 3125          // edges per bucket-build block (NE/256)
#define NODE_BLOCKS 12500 // NN/4

// scale folded into all alpha components: log2(e)/sqrt(32)
#define SL 0.25506413f

// packed table offsets (floats): PMV lane*16+i, MEV lane*16+i, BEV/UPV/WPV lane, WCV h
#define PMV 0
#define MEV 1024
#define BEV 2048
#define UPV 2112
#define WPV 2176
#define WCV 2240
#define P_TOTAL 2304

// DPP-based add over lanes: quad xor1=0xB1, xor2=0x4E, row_ror:4=0x124,
// row_ror:8=0x128 (rows are 16 lanes = one head group). VALU-pipe only.
template <int CTRL>
__device__ __forceinline__ float dpp_add(float v) {
  int m = __builtin_amdgcn_update_dpp(0, __builtin_bit_cast(int, v), CTRL, 0xF, 0xF, true);
  return v + __builtin_bit_cast(float, m);
}
__device__ __forceinline__ float row16_reduce(float v) {
  v = dpp_add<0xB1>(v);
  v = dpp_add<0x4E>(v);
  v = dpp_add<0x124>(v);
  v = dpp_add<0x128>(v);
  return v;
}

// ---------------- Kernel 0: weight precompute --------------------------
__global__ __launch_bounds__(256) void precompute_kernel(
    const float* __restrict__ Wq, const float* __restrict__ Wk,
    const float* __restrict__ bq, const float* __restrict__ bk,
    const float* __restrict__ We, float* __restrict__ P) {
  int t = threadIdx.x;
  for (int idx = t; idx < 1024; idx += 256) {
    int lane = idx >> 4, i = idx & 15;
    int h = lane >> 4, tt = lane & 15;
    float am = 0.f, ae = 0.f;
#pragma unroll
    for (int c = 0; c < 32; c++) {
      float wq = Wq[i * 128 + h * 32 + c];
      am += wq * Wk[tt * 128 + h * 32 + c];
      ae += wq * We[tt * 128 + h * 32 + c];
    }
    P[PMV + idx] = am * SL;
    P[MEV + idx] = ae * SL;
  }
  if (t < 64) {
    int h = t >> 4, tt = t & 15;
    float be = 0.f, up = 0.f, wp = 0.f;
#pragma unroll
    for (int c = 0; c < 32; c++) {
      be += bq[h * 32 + c] * We[tt * 128 + h * 32 + c];
      up += Wq[tt * 128 + h * 32 + c] * bk[h * 32 + c];
      wp += bq[h * 32 + c] * Wk[tt * 128 + h * 32 + c];
    }
    P[BEV + t] = be * SL;
    P[UPV + t] = up * SL;
    P[WPV + t] = wp * SL;
  }
  if (t < 4) {
    float wc = 0.f;
#pragma unroll
    for (int c = 0; c < 32; c++) wc += bq[t * 32 + c] * bk[t * 32 + c];
    P[WCV + t] = wc * SL;
  }
}

// ---------------- Kernel 1: node precompute + coarse hist (fused) ------
// per node (one wave): y,qe via packed-table FMA; u4/w4 via DPP reduce.
__global__ __launch_bounds__(256) void node_linear_kernel(
    const float* __restrict__ x, const float* __restrict__ P,
    const int* __restrict__ ei, int* __restrict__ hist_all,
    float* __restrict__ y, float* __restrict__ qe,
    float* __restrict__ u4, float* __restrict__ w4) {
  __shared__ int hist[NB];
  if (blockIdx.x >= NODE_BLOCKS) {
    int b = blockIdx.x - NODE_BLOCKS;  // [0,256)
    int t = threadIdx.x;
    if (t < NB) hist[t] = 0;
    __syncthreads();
    int base = b * EPB;
    for (int i = t; i < EPB; i += 256)
      atomicAdd(&hist[ei[NE + base + i] >> 8], 1);
    __syncthreads();
    if (t < NB) hist_all[t * 256 + b] = hist[t];
    return;
  }
  int wave = threadIdx.x >> 6;
  int lane = threadIdx.x & 63;
  int n = blockIdx.x * 4 + wave;
  int h = lane >> 4, t = lane & 15;

  const float4* xp = (const float4*)(x + n * 16);
  float4 X0 = xp[0], X1 = xp[1], X2 = xp[2], X3 = xp[3];
  float xr[16] = {X0.x, X0.y, X0.z, X0.w, X1.x, X1.y, X1.z, X1.w,
                  X2.x, X2.y, X2.z, X2.w, X3.x, X3.y, X3.z, X3.w};

  const float4* pm = (const float4*)(P + PMV) + lane * 4;
  const float4* me = (const float4*)(P + MEV) + lane * 4;
  float yt = 0.f, qv = P[BEV + lane];
#pragma unroll
  for (int i4 = 0; i4 < 4; i4++) {
    float4 m = pm[i4], e = me[i4];
    yt += xr[4 * i4] * m.x + xr[4 * i4 + 1] * m.y
        + xr[4 * i4 + 2] * m.z + xr[4 * i4 + 3] * m.w;
    qv += xr[4 * i4] * e.x + xr[4 * i4 + 1] * e.y
        + xr[4 * i4 + 2] * e.z + xr[4 * i4 + 3] * e.w;
  }
  y[n * 64 + lane] = yt;
  qe[n * 64 + lane] = qv;

  float pu = P[UPV + lane] * xr[t];
  float pw = P[WPV + lane] * xr[t];
  pu = row16_reduce(pu);
  pw = row16_reduce(pw);
  if (t == 0) {
    u4[n * 4 + h] = pu;
    w4[n * 4 + h] = pw + P[WCV + h];
  }
}

// ---------------- CSR build ---------------------------------------------
__global__ __launch_bounds__(256) void scan_buckets_kernel(
    int* __restrict__ hist_all, int* __restrict__ btot) {
  int wv = blockIdx.x * 4 + (threadIdx.x >> 6);
  int l = threadIdx.x & 63;
  if (wv >= NB) return;
  int base = wv * 256;
  int run = 0;
#pragma unroll
  for (int c = 0; c < 4; c++) {
    int v = hist_all[base + c * 64 + l];
    int orig = v;
#pragma unroll
    for (int d = 1; d < 64; d <<= 1) {
      int u = __shfl_up(v, d);
      if (l >= d) v += u;
    }
    hist_all[base + c * 64 + l] = run + v - orig;
    run += __shfl(v, 63);
  }
  if (l == 0) btot[wv] = run;
}

__global__ __launch_bounds__(256) void tiny_scan_kernel(
    const int* __restrict__ btot, int* __restrict__ coarse_offs) {
  __shared__ int sc[256];
  int t = threadIdx.x;
  int v = (t < NB) ? btot[t] : 0;
  sc[t] = v;
  __syncthreads();
  for (int d = 1; d < 256; d <<= 1) {
    int u = (t >= d) ? sc[t - d] : 0;
    __syncthreads();
    sc[t] += u;
    __syncthreads();
  }
  if (t < NB) coarse_offs[t] = sc[t] - v;
  if (t == NB - 1) coarse_offs[NB] = sc[t];
}

// scatter edges into coarse-bucket order, carrying {src,eid} + ea f16
__global__ __launch_bounds__(256) void bucket_scatter_kernel(
    const int* __restrict__ ei, const float* __restrict__ edge_attr,
    const int* __restrict__ cursor_all, const int* __restrict__ coarse_offs,
    int2* __restrict__ s_tmp, uint4* __restrict__ ea_tmp) {
  __shared__ int cur[NB];
  int t = threadIdx.x, b = blockIdx.x;
  if (t < NB) cur[t] = cursor_all[t * 256 + b] + coarse_offs[t];
  __syncthreads();
  int base = b * EPB;
  for (int i = t; i < EPB; i += 256) {
    int e = base + i;
    int src = ei[e], dst = ei[NE + e];
    const float4* eap = (const float4*)(edge_attr + (size_t)e * 16);
    float4 a = eap[0], bb = eap[1], c = eap[2], d = eap[3];
    uint4 u0, u1;
    __half2 hh;
    hh = __floats2half2_rn(a.x, a.y);   u0.x = *(unsigned*)&hh;
    hh = __floats2half2_rn(a.z, a.w);   u0.y = *(unsigned*)&hh;
    hh = __floats2half2_rn(bb.x, bb.y); u0.z = *(unsigned*)&hh;
    hh = __floats2half2_rn(bb.z, bb.w); u0.w = *(unsigned*)&hh;
    hh = __floats2half2_rn(c.x, c.y);   u1.x = *(unsigned*)&hh;
    hh = __floats2half2_rn(c.z, c.w);   u1.y = *(unsigned*)&hh;
    hh = __floats2half2_rn(d.x, d.y);   u1.z = *(unsigned*)&hh;
    hh = __floats2half2_rn(d.z, d.w);   u1.w = *(unsigned*)&hh;
    int pos = atomicAdd(&cur[dst >> 8], 1);
    s_tmp[pos] = make_int2(src | ((dst & 255) << 16), e);
    ea_tmp[(size_t)pos * 2]     = u0;
    ea_tmp[(size_t)pos * 2 + 1] = u1;
  }
}

// one block per bucket -> exact CSR (offs + s_se{src,eid} + s_ea)
__global__ __launch_bounds__(256) void fine_csr_kernel(
    const int2* __restrict__ s_tmp, const uint4* __restrict__ ea_tmp,
    const int* __restrict__ coarse_offs,
    int2* __restrict__ s_se, uint4* __restrict__ s_ea4,
    int* __restrict__ offs) {
  __shared__ int cnt[256], sc[256], cur[256];
  int t = threadIdx.x, b = blockIdx.x;
  int lo = coarse_offs[b], hi = coarse_offs[b + 1];
  cnt[t] = 0;
  __syncthreads();
  for (int p = lo + t; p < hi; p += 256)
    atomicAdd(&cnt[(s_tmp[p].x >> 16) & 255], 1);
  __syncthreads();
  int myc = cnt[t];
  sc[t] = myc;
  __syncthreads();
  for (int d = 1; d < 256; d <<= 1) {
    int v = (t >= d) ? sc[t - d] : 0;
    __syncthreads();
    sc[t] += v;
    __syncthreads();
  }
  int excl = sc[t] - myc;
  cur[t] = lo + excl;
  int gd = b * 256 + t;
  if (gd <= NN) offs[gd] = lo + excl;
  __syncthreads();
  for (int p = lo + t; p < hi; p += 256) {
    int2 m = s_tmp[p];
    uint4 u0 = ea_tmp[(size_t)p * 2];
    uint4 u1 = ea_tmp[(size_t)p * 2 + 1];
    int pos = atomicAdd(&cur[(m.x >> 16) & 255], 1);
    s_se[pos] = make_int2(m.x & 0xFFFF, m.y);
    s_ea4[(size_t)pos * 2]     = u0;
    s_ea4[(size_t)pos * 2 + 1] = u1;
  }
}

// ---------------- Kernel 3: aggregation + A/C epilogue -----------------
// one wave per dst node; 16 lanes/head; sequential s_se/s_ea; 8-edge ILP;
// dot reduce via DPP (VALU pipe, zero DS ops in loop).
__global__ __launch_bounds__(256) void aggregate_kernel(
    const float* __restrict__ y, const float* __restrict__ qe,
    const float* __restrict__ u4, const float* __restrict__ w4,
    const float* __restrict__ x, const __half* __restrict__ s_ea,
    const int2* __restrict__ s_se,
    const float* __restrict__ We, const float* __restrict__ Wv,
    const float* __restrict__ bv,
    const float* __restrict__ Wskip, const float* __restrict__ bskip,
    const float* __restrict__ W1, const float* __restrict__ b1,
    const int* __restrict__ offs,
    __half* __restrict__ Ah, __half* __restrict__ Cbh) {
  int wave = threadIdx.x >> 6, lane = threadIdx.x & 63;
  int n = blockIdx.x * 4 + wave;
  int h = lane >> 4, t = lane & 15;
  int base = h * 32 + t;
  int gb = lane & 48;

  float yt = y[n * 64 + lane];
  float qet = qe[n * 64 + lane];
  float u_n = u4[n * 4 + h];
  int off = offs[n], end = offs[n + 1];

  float s = 0.f, ax = 0.f, ae = 0.f;
  int j = off;
  for (; j + 8 <= end; j += 8) {
    const uint4* sp = (const uint4*)&s_se[j];
    uint4 sa = sp[0], sb = sp[1], sc4 = sp[2], sd = sp[3];
    int src[8] = {(int)sa.x, (int)sa.z, (int)sb.x, (int)sb.z,
                  (int)sc4.x, (int)sc4.z, (int)sd.x, (int)sd.z};
    float xs[8], ea[8], uw[8];
#pragma unroll
    for (int u = 0; u < 8; u++) {
      xs[u] = x[(unsigned)src[u] * 16u + (unsigned)t];
      ea[u] = __half2float(s_ea[(size_t)(j + u) * 16 + t]);
      uw[u] = w4[(unsigned)src[u] * 4u + (unsigned)h];
    }
    float p[8];
#pragma unroll
    for (int u = 0; u < 8; u++) p[u] = fmaf(yt, xs[u], qet * ea[u]);
#pragma unroll
    for (int u = 0; u < 8; u++) p[u] = row16_reduce(p[u]);
#pragma unroll
    for (int u = 0; u < 8; u++) {
      float wgt = exp2f(p[u] + u_n + uw[u]);
      s += wgt;
      ax = fmaf(wgt, xs[u], ax);
      ae = fmaf(wgt, ea[u], ae);
    }
  }
  for (; j < end; j++) {
    int srcu = s_se[j].x;
    float xs = x[(unsigned)srcu * 16u + (unsigned)t];
    float ea_ = __half2float(s_ea[(size_t)j * 16 + t]);
    float uw = w4[(unsigned)srcu * 4u + (unsigned)h];
    float p = fmaf(yt, xs, qet * ea_);
    p = row16_reduce(p);
    float wgt = exp2f(p + u_n + uw);
    s += wgt;
    ax = fmaf(wgt, xs, ax);
    ae = fmaf(wgt, ea_, ae);
  }

  float inv = (end > off) ? 1.f / s : 0.f;
  float dflag = (end > off) ? 1.f : 0.f;
  float axn = ax * inv, aen = ae * inv;
  float r0 = dflag * bv[base], r1 = dflag * bv[base + 16];
#pragma unroll
  for (int i = 0; i < 16; i++) {
    float axi = __shfl(axn, gb | i);
    float aei = __shfl(aen, gb | i);
    r0 += axi * Wv[i * 128 + base]      + aei * We[i * 128 + base];
    r1 += axi * Wv[i * 128 + base + 16] + aei * We[i * 128 + base + 16];
  }
  // mean over heads
  r0 += __shfl_xor(r0, 16); r0 += __shfl_xor(r0, 32);
  r1 += __shfl_xor(r1, 16); r1 += __shfl_xor(r1, 32);

  // skip connection
  float sk0 = bskip[t], sk1 = bskip[t + 16];
#pragma unroll
  for (int i = 0; i < 16; i++) {
    float xi = x[n * 16 + i];
    sk0 += xi * Wskip[i * 32 + t];
    sk1 += xi * Wskip[i * 32 + t + 16];
  }
  float o0 = 0.25f * r0 + sk0;  // out[n][t]
  float o1 = 0.25f * r1 + sk1;  // out[n][t+16]

  // A[n][jj] = out@W1[0:32]; Cb[n][jj] = out@W1[48:80] + b1  (stored f16)
  int jj = lane & 31;
  int roff = (lane < 32) ? 0 : 48;
  float acc = (lane < 32) ? 0.f : b1[jj];
#pragma unroll
  for (int i = 0; i < 16; i++) {
    float oi = __shfl(o0, i);
    acc += oi * W1[(roff + i) * 32 + jj];
  }
#pragma unroll
  for (int i = 0; i < 16; i++) {
    float oi = __shfl(o1, i);
    acc += oi * W1[(roff + 16 + i) * 32 + jj];
  }
  float nb = __shfl_xor(acc, 1);
  if ((lane & 1) == 0) {
    __half2 hh = __floats2half2_rn(acc, nb);
    if (lane < 32) *(__half2*)(Ah  + n * 32 + jj) = hh;
    else           *(__half2*)(Cbh + n * 32 + jj) = hh;
  }
}

// ---------------- Kernel 4: per-edge MLP, CSR order --------------------
__global__ __launch_bounds__(256) void mlp_kernel(
    const int2* __restrict__ s_se, const __half* __restrict__ s_ea,
    const int* __restrict__ offs,
    const __half* __restrict__ Ah, const __half* __restrict__ Cbh,
    const float* __restrict__ W1, const float* __restrict__ W2,
    const float* __restrict__ b2v, float* __restrict__ out) {
  int wave = threadIdx.x >> 6, lane = threadIdx.x & 63;
  int n = blockIdx.x * 4 + wave;
  int g = lane >> 5, l = lane & 31;

  float w1e[16];
#pragma unroll
  for (int i = 0; i < 16; i++) w1e[i] = W1[(32 + i) * 32 + l];
  float w2j = W2[l];
  float b2s = b2v[0];
  float cb = __half2float(Cbh[n * 32 + l]);
  int off = offs[n], end = offs[n + 1];

  for (int p = off + g; p < end; p += 2) {
    int2 se = s_se[p];
    float a = __half2float(Ah[(unsigned)se.x * 32u + l]);
    const uint4* eap = (const uint4*)(s_ea + (size_t)p * 16);
    uint4 u0 = eap[0], u1 = eap[1];
    float hsum = a + cb;
    const __half2* hp0 = (const __half2*)&u0;
    const __half2* hp1 = (const __half2*)&u1;
#pragma unroll
    for (int i = 0; i < 4; i++) {
      float2 f0 = __half22float2(hp0[i]);
      hsum += f0.x * w1e[2 * i] + f0.y * w1e[2 * i + 1];
      float2 f1 = __half22float2(hp1[i]);
      hsum += f1.x * w1e[8 + 2 * i] + f1.y * w1e[8 + 2 * i + 1];
    }
    float hv = fmaxf(hsum, 0.f) * w2j;
    hv += __shfl_xor(hv, 1); hv += __shfl_xor(hv, 2);
    hv += __shfl_xor(hv, 4); hv += __shfl_xor(hv, 8);
    hv += __shfl_xor(hv, 16);
    if (l == 0) out[se.y] = hv + b2s;
  }
}

// ---------------- launch -----------------------------------------------
extern "C" void kernel_launch(void* const* d_in, const int* in_sizes, int n_in,
                              void* d_out, int out_size, void* d_ws, size_t ws_size,
                              hipStream_t stream) {
  const float* x         = (const float*)d_in[0];
  const int*   ei        = (const int*)d_in[1];
  const float* edge_attr = (const float*)d_in[2];
  const float* Wq = (const float*)d_in[3],  *bq = (const float*)d_in[4];
  const float* Wk = (const float*)d_in[5],  *bk = (const float*)d_in[6];
  const float* Wv = (const float*)d_in[7],  *bv = (const float*)d_in[8];
  const float* We = (const float*)d_in[9];
  const float* Wskip = (const float*)d_in[10], *bskip = (const float*)d_in[11];
  const float* W1 = (const float*)d_in[12], *b1 = (const float*)d_in[13];
  const float* W2 = (const float*)d_in[14], *b2 = (const float*)d_in[15];
  float* out = (float*)d_out;

  // workspace layout (~91.7 MB); Ah/Cbh ALIAS ea_tmp (dead after fine_csr)
  char* w = (char*)d_ws;
  float*   y    = (float*)w;            w += (size_t)NN * 64 * 4;   // 12.8 MB
  float*   qe   = (float*)w;            w += (size_t)NN * 64 * 4;   // 12.8 MB
  float*   u4   = (float*)w;            w += (size_t)NN * 4 * 4;    // 0.8 MB
  float*   w4   = (float*)w;            w += (size_t)NN * 4 * 4;    // 0.8 MB
  int2*    s_se = (int2*)w;             w += (size_t)NE * 8;        // 6.4 MB
  int2*    s_tmp = (int2*)w;            w += (size_t)NE * 8;        // 6.4 MB
  uint4*   s_ea4 = (uint4*)w;           w += (size_t)NE * 32;       // 25.6 MB
  uint4*   ea_tmp = (uint4*)w;          // 25.6 MB (Ah, Cbh alias inside)
  __half*  Ah   = (__half*)ea_tmp;                          // 3.2 MB
  __half*  Cbh  = (__half*)((char*)ea_tmp + (size_t)NN * 32 * 2); // 3.2 MB
  w += (size_t)NE * 32;
  int*     hist_all = (int*)w;          w += (size_t)256 * 256 * 4; // 256 KB
  int*     btot = (int*)w;              w += 256 * 4;
  int*     coarse_offs = (int*)w;       w += 256 * 4;
  int*     offs = (int*)w;              w += ((size_t)NN + 1) * 4;
  float*   P    = (float*)w;            w += (size_t)P_TOTAL * 4;

  precompute_kernel<<<1, 256, 0, stream>>>(Wq, Wk, bq, bk, We, P);
  node_linear_kernel<<<NODE_BLOCKS + 256, 256, 0, stream>>>(
      x, P, ei, hist_all, y, qe, u4, w4);
  scan_buckets_kernel<<<49, 256, 0, stream>>>(hist_all, btot);
  tiny_scan_kernel<<<1, 256, 0, stream>>>(btot, coarse_offs);
  bucket_scatter_kernel<<<256, 256, 0, stream>>>(ei, edge_attr, hist_all,
                                                 coarse_offs, s_tmp, ea_tmp);
  fine_csr_kernel<<<NB, 256, 0, stream>>>(s_tmp, ea_tmp, coarse_offs,
                                          s_se, s_ea4, offs);
  aggregate_kernel<<<NN / 4, 256, 0, stream>>>(y, qe, u4, w4, x,
                                               (const __half*)s_ea4, s_se,
                                               We, Wv, bv, Wskip, bskip, W1, b1,
                                               offs, Ah, Cbh);
  mlp_kernel<<<NN / 4, 256, 0, stream>>>(s_se, (const __half*)s_ea4, offs,
                                         Ah, Cbh, W1, W2, b2, out);
}